// Round 1
// baseline (1365.874 us; speedup 1.0000x reference)
//
#include <hip/hip_runtime.h>
#include <stdint.h>

#define N_NODES 100000
#define N_EDGES 1600000
#define HDIM    128
#define KSTEPS  10
#define NZONE   8
#define ZDIV    12500u            // N_NODES / NZONE (dst zones for fill)

// ---- src-zone sorted CSR ----
#define NZS     8                 // src zones for gather locality
#define SZDIV   12500u            // N_NODES / NZS
#define NBINS   (NZS * N_NODES)   // 800000 zone-major bins: bin = sz*N + dst

typedef unsigned int uint;

// ---- CSR-build scan config ----
#define SCAN_T     256
#define SCAN_I     4
#define SCAN_ELEMS (SCAN_T * SCAN_I)                        // 1024
#define SCAN_NB    ((NBINS + SCAN_ELEMS - 1) / SCAN_ELEMS)  // 782
#define S2_I       4                                        // 256*4 >= 782

// ---- bf16x2 helpers (RNE) ----
__device__ inline float2 bf2_to_f2(uint v) {
    float2 r;
    r.x = __uint_as_float(v << 16);
    r.y = __uint_as_float(v & 0xffff0000u);
    return r;
}
__device__ inline uint f_to_bf_bits(float f) {        // returns bf16 in low 16
    uint u = __float_as_uint(f);
    return (u + 0x7fffu + ((u >> 16) & 1u)) >> 16;
}
__device__ inline uint f2_to_bf2(float x, float y) {
    return f_to_bf_bits(x) | (f_to_bf_bits(y) << 16);
}

// ------- fused degree-count + in-bin position (one atomic pass) -------
// bin = (src/SZDIV)*N_NODES + dst  (zone-MAJOR so each zone's edges are
// contiguous in col for every node range)
__global__ void k_countpos(const int* __restrict__ eidx, int* __restrict__ cnt,
                           int* __restrict__ pos) {
    int e0 = (blockIdx.x * blockDim.x + threadIdx.x) * 4;
    if (e0 < N_EDGES) {
        int4 s4 = *(const int4*)&eidx[e0];
        int4 d4 = *(const int4*)&eidx[N_EDGES + e0];
        int4 p;
        p.x = atomicAdd(&cnt[(int)((uint)s4.x / SZDIV) * N_NODES + d4.x], 1);
        p.y = atomicAdd(&cnt[(int)((uint)s4.y / SZDIV) * N_NODES + d4.y], 1);
        p.z = atomicAdd(&cnt[(int)((uint)s4.z / SZDIV) * N_NODES + d4.z], 1);
        p.w = atomicAdd(&cnt[(int)((uint)s4.w / SZDIV) * N_NODES + d4.w], 1);
        *(int4*)&pos[e0] = p;
    }
}

// ---------------- exclusive scan over NBINS (3-phase) ----------------
__global__ void k_scan1(const int* __restrict__ cnt, int* __restrict__ rp,
                        int* __restrict__ bsum) {
    __shared__ int s[SCAN_T];
    int tid  = threadIdx.x;
    int base = blockIdx.x * SCAN_ELEMS + tid * SCAN_I;
    int v[SCAN_I];
    int loc = 0;
#pragma unroll
    for (int j = 0; j < SCAN_I; ++j) {
        int idx = base + j;
        v[j] = (idx < NBINS) ? cnt[idx] : 0;
        loc += v[j];
    }
    s[tid] = loc;
    __syncthreads();
    for (int off = 1; off < SCAN_T; off <<= 1) {
        int t = (tid >= off) ? s[tid - off] : 0;
        __syncthreads();
        s[tid] += t;
        __syncthreads();
    }
    int run = s[tid] - loc;   // exclusive prefix for this thread
#pragma unroll
    for (int j = 0; j < SCAN_I; ++j) {
        int idx = base + j;
        if (idx < NBINS) rp[idx] = run;
        run += v[j];
    }
    if (tid == SCAN_T - 1) bsum[blockIdx.x] = s[SCAN_T - 1];
}

// parallel block-sum scan (782 elems; serial loop here would be a hotspot)
__global__ void k_scan2(const int* __restrict__ bsum, int* __restrict__ boff,
                        int* __restrict__ rp) {
    __shared__ int s[SCAN_T];
    int tid = threadIdx.x;
    int v[S2_I];
    int loc = 0;
#pragma unroll
    for (int j = 0; j < S2_I; ++j) {
        int idx = tid * S2_I + j;
        v[j] = (idx < SCAN_NB) ? bsum[idx] : 0;
        loc += v[j];
    }
    s[tid] = loc;
    __syncthreads();
    for (int off = 1; off < SCAN_T; off <<= 1) {
        int t = (tid >= off) ? s[tid - off] : 0;
        __syncthreads();
        s[tid] += t;
        __syncthreads();
    }
    int run = s[tid] - loc;
#pragma unroll
    for (int j = 0; j < S2_I; ++j) {
        int idx = tid * S2_I + j;
        if (idx < SCAN_NB) boff[idx] = run;
        run += v[j];
    }
    if (tid == SCAN_T - 1) rp[NBINS] = s[SCAN_T - 1];
}

__global__ void k_scan3(int* __restrict__ rp, const int* __restrict__ boff) {
    int off = boff[blockIdx.x];
#pragma unroll
    for (int j = 0; j < SCAN_I; ++j) {
        int i = blockIdx.x * SCAN_ELEMS + threadIdx.x + j * SCAN_T;
        if (i < NBINS) rp[i] += off;
    }
}

// -------- dinv = rsqrt(1+deg), dsq = sqrt(1+deg); deg from zone-major rpz --------
__global__ void k_dinv(const int* __restrict__ rpz, float* __restrict__ dinv,
                       float* __restrict__ dsq) {
    int i = blockIdx.x * blockDim.x + threadIdx.x;
    if (i < N_NODES) {
        int deg = 0;
#pragma unroll
        for (int z = 0; z < NZS; ++z)
            deg += rpz[(size_t)z * N_NODES + i + 1] - rpz[(size_t)z * N_NODES + i];
        float d = 1.0f + (float)deg;
        dinv[i] = rsqrtf(d);
        dsq[i]  = sqrtf(d);
    }
}

// ------- dst-zone-partitioned CSR fill, atomic-free -------
#define FCHUNK 8192
#define FECH   ((N_EDGES + FCHUNK - 1) / FCHUNK)
__global__ __launch_bounds__(256)
void k_fill2(const int* __restrict__ eidx, const int* __restrict__ rpz,
             const int* __restrict__ pos, int* __restrict__ col) {
    uint zone = blockIdx.x;
    int  base = blockIdx.y * FCHUNK;
#pragma unroll
    for (int i = 0; i < FCHUNK / 1024; ++i) {     // 8 iters x 1024 edges/block
        int e0 = base + (i * 256 + (int)threadIdx.x) * 4;
        if (e0 < N_EDGES) {
            int4 d4 = *(const int4*)&eidx[N_EDGES + e0];
            int4 s4 = *(const int4*)&eidx[e0];
            int4 p4 = *(const int4*)&pos[e0];
            if ((uint)d4.x / ZDIV == zone)
                col[rpz[(int)((uint)s4.x / SZDIV) * N_NODES + d4.x] + p4.x] = s4.x;
            if ((uint)d4.y / ZDIV == zone)
                col[rpz[(int)((uint)s4.y / SZDIV) * N_NODES + d4.y] + p4.y] = s4.y;
            if ((uint)d4.z / ZDIV == zone)
                col[rpz[(int)((uint)s4.z / SZDIV) * N_NODES + d4.z] + p4.z] = s4.z;
            if ((uint)d4.w / ZDIV == zone)
                col[rpz[(int)((uint)s4.w / SZDIV) * N_NODES + d4.w] + p4.w] = s4.w;
        }
    }
}

// ---------------- GEMM1: u0 = bf16( dinv * relu(x @ W1 + b1) ) ----------------
#define KCH 64
__global__ __launch_bounds__(256)
void k_gemm1(const float* __restrict__ x, const float* __restrict__ W,
             const float* __restrict__ bias, const float* __restrict__ dinv,
             uint* __restrict__ out) {
    __shared__ __align__(16) float wlds[KCH][HDIM];     // 32 KB
    __shared__ __align__(16) float xs[32][KCH + 1];     // ~8.3 KB
    int tid  = threadIdx.x;
    int tx   = tid & 31, ty = tid >> 5;
    int row0 = blockIdx.x * 32;

    float4 bc = *(const float4*)&bias[tx * 4];

    float acc[4][4] = {};
    for (int kc = 0; kc < HDIM; kc += KCH) {
#pragma unroll
        for (int i = 0; i < 8; ++i) {
            int id = tid + i * 256;
            int kk = id >> 5, n4 = id & 31;
            *(float4*)&wlds[kk][n4 * 4] =
                *(const float4*)&W[(size_t)(kc + kk) * HDIM + n4 * 4];
        }
#pragma unroll
        for (int i = 0; i < 2; ++i) {
            int id = tid + i * 256;
            int r = id >> 4, c4 = id & 15;
            float4 v = *(const float4*)&x[(size_t)(row0 + r) * HDIM + kc + c4 * 4];
            xs[r][c4 * 4 + 0] = v.x;
            xs[r][c4 * 4 + 1] = v.y;
            xs[r][c4 * 4 + 2] = v.z;
            xs[r][c4 * 4 + 3] = v.w;
        }
        __syncthreads();
#pragma unroll 8
        for (int kk = 0; kk < KCH; ++kk) {
            float4 b4 = *(const float4*)&wlds[kk][tx * 4];
            float a0 = xs[ty * 4 + 0][kk];
            float a1 = xs[ty * 4 + 1][kk];
            float a2 = xs[ty * 4 + 2][kk];
            float a3 = xs[ty * 4 + 3][kk];
            acc[0][0] += a0 * b4.x; acc[0][1] += a0 * b4.y; acc[0][2] += a0 * b4.z; acc[0][3] += a0 * b4.w;
            acc[1][0] += a1 * b4.x; acc[1][1] += a1 * b4.y; acc[1][2] += a1 * b4.z; acc[1][3] += a1 * b4.w;
            acc[2][0] += a2 * b4.x; acc[2][1] += a2 * b4.y; acc[2][2] += a2 * b4.z; acc[2][3] += a2 * b4.w;
            acc[3][0] += a3 * b4.x; acc[3][1] += a3 * b4.y; acc[3][2] += a3 * b4.z; acc[3][3] += a3 * b4.w;
        }
        __syncthreads();
    }
#pragma unroll
    for (int r = 0; r < 4; ++r) {
        int row = row0 + ty * 4 + r;
        float di = dinv[row];
        float v0 = fmaxf(acc[r][0] + bc.x, 0.0f) * di;
        float v1 = fmaxf(acc[r][1] + bc.y, 0.0f) * di;
        float v2 = fmaxf(acc[r][2] + bc.z, 0.0f) * di;
        float v3 = fmaxf(acc[r][3] + bc.w, 0.0f) * di;
        uint2 p;
        p.x = f2_to_bf2(v0, v1);
        p.y = f2_to_bf2(v2, v3);
        *(uint2*)&out[(size_t)row * 64 + tx * 2] = p;   // row = 64 uints (128 bf16)
    }
}

// ---------------- GEMM2: out = (dsq * bf16 u) @ W2 + b2, fp32 out ----------------
__global__ __launch_bounds__(256)
void k_gemm2(const uint* __restrict__ u, const float* __restrict__ W,
             const float* __restrict__ bias, const float* __restrict__ dsq,
             float* __restrict__ out) {
    __shared__ __align__(16) float wlds[KCH][HDIM];
    __shared__ __align__(16) float xs[32][KCH + 1];
    int tid  = threadIdx.x;
    int tx   = tid & 31, ty = tid >> 5;
    int row0 = blockIdx.x * 32;

    float4 bc = *(const float4*)&bias[tx * 4];

    float acc[4][4] = {};
    for (int kc = 0; kc < HDIM; kc += KCH) {
#pragma unroll
        for (int i = 0; i < 8; ++i) {
            int id = tid + i * 256;
            int kk = id >> 5, n4 = id & 31;
            *(float4*)&wlds[kk][n4 * 4] =
                *(const float4*)&W[(size_t)(kc + kk) * HDIM + n4 * 4];
        }
#pragma unroll
        for (int i = 0; i < 2; ++i) {
            int id = tid + i * 256;
            int r = id >> 4, c4 = id & 15;
            float ds = dsq[row0 + r];
            uint2 v = *(const uint2*)&u[(size_t)(row0 + r) * 64 + (kc >> 1) + c4 * 2];
            float2 f0 = bf2_to_f2(v.x);
            float2 f1 = bf2_to_f2(v.y);
            xs[r][c4 * 4 + 0] = f0.x * ds;
            xs[r][c4 * 4 + 1] = f0.y * ds;
            xs[r][c4 * 4 + 2] = f1.x * ds;
            xs[r][c4 * 4 + 3] = f1.y * ds;
        }
        __syncthreads();
#pragma unroll 8
        for (int kk = 0; kk < KCH; ++kk) {
            float4 b4 = *(const float4*)&wlds[kk][tx * 4];
            float a0 = xs[ty * 4 + 0][kk];
            float a1 = xs[ty * 4 + 1][kk];
            float a2 = xs[ty * 4 + 2][kk];
            float a3 = xs[ty * 4 + 3][kk];
            acc[0][0] += a0 * b4.x; acc[0][1] += a0 * b4.y; acc[0][2] += a0 * b4.z; acc[0][3] += a0 * b4.w;
            acc[1][0] += a1 * b4.x; acc[1][1] += a1 * b4.y; acc[1][2] += a1 * b4.z; acc[1][3] += a1 * b4.w;
            acc[2][0] += a2 * b4.x; acc[2][1] += a2 * b4.y; acc[2][2] += a2 * b4.z; acc[2][3] += a2 * b4.w;
            acc[3][0] += a3 * b4.x; acc[3][1] += a3 * b4.y; acc[3][2] += a3 * b4.z; acc[3][3] += a3 * b4.w;
        }
        __syncthreads();
    }
#pragma unroll
    for (int r = 0; r < 4; ++r) {
        int row = row0 + ty * 4 + r;
        float4 v;
        v.x = acc[r][0] + bc.x;
        v.y = acc[r][1] + bc.y;
        v.z = acc[r][2] + bc.z;
        v.w = acc[r][3] + bc.w;
        *(float4*)&out[(size_t)row * HDIM + tx * 4] = v;
    }
}

// ---- APPNP step, zone-phased gather: wave owns JPW nodes, sweeps src zones ----
// u' = 0.9*dinv^2*(sum_{s in N(n)} u[s] + u[n]) + 0.1*u0
// col is zone-major sorted: for zone z, the wave's JPW nodes' edges are
// contiguous; all waves sweep z=0..7 together -> per-XCD L2 working set ~3.2MB.
#define JPW 16
__global__ __launch_bounds__(256, 6)
void k_prop(const uint* __restrict__ uin, const uint* __restrict__ u0,
            uint* __restrict__ uout, const int* __restrict__ col,
            const int* __restrict__ rpz, const float* __restrict__ dinv) {
    int wid  = __builtin_amdgcn_readfirstlane((int)(blockIdx.x * 4 + (threadIdx.x >> 6)));
    int lane = threadIdx.x & 63;
    int n0   = wid * JPW;
    if (n0 >= N_NODES) return;

    float ax[JPW], ay[JPW];
#pragma unroll
    for (int j = 0; j < JPW; ++j) { ax[j] = 0.0f; ay[j] = 0.0f; }

    for (int z = 0; z < NZS; ++z) {
        const int* bp = &rpz[(size_t)z * N_NODES + n0];
        int B[JPW + 1];
#pragma unroll
        for (int i = 0; i <= JPW; ++i) B[i] = bp[i];
#pragma unroll
        for (int g = 0; g < JPW / 4; ++g) {
            int ea = B[4 * g + 0], Ea = B[4 * g + 1];
            int eb = B[4 * g + 1], Eb = B[4 * g + 2];
            int ec = B[4 * g + 2], Ec = B[4 * g + 3];
            int ed = B[4 * g + 3], Ed = B[4 * g + 4];
            while ((ea < Ea) | (eb < Eb) | (ec < Ec) | (ed < Ed)) {
                bool pa = ea < Ea, pb = eb < Eb, pc = ec < Ec, pd = ed < Ed;
                uint ba, bb, bc, bd;
                if (pa) ba = uin[(size_t)col[ea] * 64 + lane];
                if (pb) bb = uin[(size_t)col[eb] * 64 + lane];
                if (pc) bc = uin[(size_t)col[ec] * 64 + lane];
                if (pd) bd = uin[(size_t)col[ed] * 64 + lane];
                if (pa) { float2 f = bf2_to_f2(ba); ax[4*g+0] += f.x; ay[4*g+0] += f.y; ++ea; }
                if (pb) { float2 f = bf2_to_f2(bb); ax[4*g+1] += f.x; ay[4*g+1] += f.y; ++eb; }
                if (pc) { float2 f = bf2_to_f2(bc); ax[4*g+2] += f.x; ay[4*g+2] += f.y; ++ec; }
                if (pd) { float2 f = bf2_to_f2(bd); ax[4*g+3] += f.x; ay[4*g+3] += f.y; ++ed; }
            }
        }
    }

#pragma unroll
    for (int j = 0; j < JPW; ++j) {
        int n = n0 + j;
        size_t self = (size_t)n * 64 + lane;
        uint usv = uin[self];
        uint uzv = __builtin_nontemporal_load(&u0[self]);
        float di = dinv[n];
        float w  = 0.9f * di * di;
        float2 us = bf2_to_f2(usv);
        float2 uz = bf2_to_f2(uzv);
        float ox = w * (ax[j] + us.x) + 0.1f * uz.x;
        float oy = w * (ay[j] + us.y) + 0.1f * uz.y;
        __builtin_nontemporal_store(f2_to_bf2(ox, oy), &uout[self]);
    }
}

extern "C" void kernel_launch(void* const* d_in, const int* in_sizes, int n_in,
                              void* d_out, int out_size, void* d_ws, size_t ws_size,
                              hipStream_t stream) {
    (void)in_sizes; (void)n_in; (void)out_size; (void)ws_size;
    const float* x  = (const float*)d_in[0];
    const int*   ei = (const int*)d_in[1];
    const float* W1 = (const float*)d_in[2];
    const float* b1 = (const float*)d_in[3];
    const float* W2 = (const float*)d_in[4];
    const float* b2 = (const float*)d_in[5];
    float* out = (float*)d_out;

    char* ws = (char*)d_ws;
    size_t off = 0;
    auto alloc = [&](size_t bytes) -> void* {
        void* p = ws + off;
        off += (bytes + 255) & ~(size_t)255;
        return p;
    };
    uint*  u0   = (uint*)alloc(sizeof(uint) * (size_t)N_NODES * 64);   // bf16x2 rows
    uint*  uA   = (uint*)alloc(sizeof(uint) * (size_t)N_NODES * 64);
    uint*  uB   = (uint*)alloc(sizeof(uint) * (size_t)N_NODES * 64);
    int*   col  = (int*)alloc(sizeof(int) * N_EDGES);
    int*   rpz  = (int*)alloc(sizeof(int) * (NBINS + 1));
    float* dinv = (float*)alloc(sizeof(float) * N_NODES);
    float* dsq  = (float*)alloc(sizeof(float) * N_NODES);
    int*   bsum = (int*)alloc(sizeof(int) * SCAN_NB);
    int*   boff = (int*)alloc(sizeof(int) * SCAN_NB);
    // cnt2 dead after k_scan1 (uA first written by k_prop k=0, after fill);
    // pos dead after k_fill2 (uB first written by k_prop k=1).
    int*   cnt2 = (int*)uA;
    int*   pos  = (int*)uB;

    hipMemsetAsync(cnt2, 0, sizeof(int) * NBINS, stream);

    k_countpos<<<(N_EDGES / 4 + 255) / 256, 256, 0, stream>>>(ei, cnt2, pos);
    k_scan1<<<SCAN_NB, SCAN_T, 0, stream>>>(cnt2, rpz, bsum);
    k_scan2<<<1, SCAN_T, 0, stream>>>(bsum, boff, rpz);
    k_scan3<<<SCAN_NB, SCAN_T, 0, stream>>>(rpz, boff);
    k_dinv<<<(N_NODES + 255) / 256, 256, 0, stream>>>(rpz, dinv, dsq);
    {
        dim3 g(NZONE, FECH);
        k_fill2<<<g, 256, 0, stream>>>(ei, rpz, pos, col);
    }

    k_gemm1<<<N_NODES / 32, 256, 0, stream>>>(x, W1, b1, dinv, u0);

    const uint* uin = u0;
    uint* uout = uA;
    int nblk = (N_NODES / JPW + 3) / 4;   // 1563 blocks of 4 waves
    for (int k = 0; k < KSTEPS; ++k) {
        k_prop<<<nblk, 256, 0, stream>>>(uin, u0, uout, col, rpz, dinv);
        uin = uout;
        uout = (uout == uA) ? uB : uA;
    }
    k_gemm2<<<N_NODES / 32, 256, 0, stream>>>(uin, W2, b2, dsq, out);
}

// Round 2
// 965.854 us; speedup vs baseline: 1.4142x; 1.4142x over previous
//
#include <hip/hip_runtime.h>
#include <stdint.h>

#define N_NODES 100000
#define N_EDGES 1600000
#define HDIM    128
#define KSTEPS  10
#define NZONE   8
#define ZDIV    12500u            // N_NODES / NZONE (dst zones, XCD-local atomics)

// ---- CSR bins: dst-major, src-zone-minor -> per-node contiguous edges,
// sorted by src zone (ascending src sweep => generation-level L2 locality)
#define NZS     8
#define SZDIV   12500u
#define NBINS   (N_NODES * NZS)   // 800000

typedef unsigned int uint;

// ---- CSR-build scan config ----
#define SCAN_T     256
#define SCAN_I     4
#define SCAN_ELEMS (SCAN_T * SCAN_I)                        // 1024
#define SCAN_NB    ((NBINS + SCAN_ELEMS - 1) / SCAN_ELEMS)  // 782
#define S2_I       4                                        // 256*4 >= 782

// ---- bf16x2 helpers (RNE) ----
__device__ inline float2 bf2_to_f2(uint v) {
    float2 r;
    r.x = __uint_as_float(v << 16);
    r.y = __uint_as_float(v & 0xffff0000u);
    return r;
}
__device__ inline uint f_to_bf_bits(float f) {        // returns bf16 in low 16
    uint u = __float_as_uint(f);
    return (u + 0x7fffu + ((u >> 16) & 1u)) >> 16;
}
__device__ inline uint f2_to_bf2(float x, float y) {
    return f_to_bf_bits(x) | (f_to_bf_bits(y) << 16);
}

// ------- XCD-local degree count: class z (blockIdx.x) owns dst zone z -------
// grid = (NZONE, FECH); linear block id = z + NZONE*c -> one zone per XCD
// (round-robin heuristic) -> each zone's cnt lines live in ONE L2, no bounce.
#define FCHUNK 8192
#define FECH   ((N_EDGES + FCHUNK - 1) / FCHUNK)
__global__ __launch_bounds__(256)
void k_count(const int* __restrict__ eidx, int* __restrict__ cnt) {
    uint zone = blockIdx.x;
    int  base = blockIdx.y * FCHUNK;
#pragma unroll
    for (int i = 0; i < FCHUNK / 1024; ++i) {
        int e0 = base + (i * 256 + (int)threadIdx.x) * 4;
        if (e0 < N_EDGES) {
            int4 d4 = *(const int4*)&eidx[N_EDGES + e0];
            int4 s4 = *(const int4*)&eidx[e0];
            if ((uint)d4.x / ZDIV == zone)
                atomicAdd(&cnt[d4.x * NZS + (int)((uint)s4.x / SZDIV)], 1);
            if ((uint)d4.y / ZDIV == zone)
                atomicAdd(&cnt[d4.y * NZS + (int)((uint)s4.y / SZDIV)], 1);
            if ((uint)d4.z / ZDIV == zone)
                atomicAdd(&cnt[d4.z * NZS + (int)((uint)s4.z / SZDIV)], 1);
            if ((uint)d4.w / ZDIV == zone)
                atomicAdd(&cnt[d4.w * NZS + (int)((uint)s4.w / SZDIV)], 1);
        }
    }
}

// ---------------- exclusive scan over NBINS (3-phase) ----------------
__global__ void k_scan1(const int* __restrict__ cnt, int* __restrict__ rp,
                        int* __restrict__ bsum) {
    __shared__ int s[SCAN_T];
    int tid  = threadIdx.x;
    int base = blockIdx.x * SCAN_ELEMS + tid * SCAN_I;
    int v[SCAN_I];
    int loc = 0;
#pragma unroll
    for (int j = 0; j < SCAN_I; ++j) {
        int idx = base + j;
        v[j] = (idx < NBINS) ? cnt[idx] : 0;
        loc += v[j];
    }
    s[tid] = loc;
    __syncthreads();
    for (int off = 1; off < SCAN_T; off <<= 1) {
        int t = (tid >= off) ? s[tid - off] : 0;
        __syncthreads();
        s[tid] += t;
        __syncthreads();
    }
    int run = s[tid] - loc;   // exclusive prefix for this thread
#pragma unroll
    for (int j = 0; j < SCAN_I; ++j) {
        int idx = base + j;
        if (idx < NBINS) rp[idx] = run;
        run += v[j];
    }
    if (tid == SCAN_T - 1) bsum[blockIdx.x] = s[SCAN_T - 1];
}

// parallel block-sum scan (782 elems)
__global__ void k_scan2(const int* __restrict__ bsum, int* __restrict__ boff,
                        int* __restrict__ rp) {
    __shared__ int s[SCAN_T];
    int tid = threadIdx.x;
    int v[S2_I];
    int loc = 0;
#pragma unroll
    for (int j = 0; j < S2_I; ++j) {
        int idx = tid * S2_I + j;
        v[j] = (idx < SCAN_NB) ? bsum[idx] : 0;
        loc += v[j];
    }
    s[tid] = loc;
    __syncthreads();
    for (int off = 1; off < SCAN_T; off <<= 1) {
        int t = (tid >= off) ? s[tid - off] : 0;
        __syncthreads();
        s[tid] += t;
        __syncthreads();
    }
    int run = s[tid] - loc;
#pragma unroll
    for (int j = 0; j < S2_I; ++j) {
        int idx = tid * S2_I + j;
        if (idx < SCAN_NB) boff[idx] = run;
        run += v[j];
    }
    if (tid == SCAN_T - 1) rp[NBINS] = s[SCAN_T - 1];
}

__global__ void k_scan3(int* __restrict__ rp, const int* __restrict__ boff) {
    int off = boff[blockIdx.x];
#pragma unroll
    for (int j = 0; j < SCAN_I; ++j) {
        int i = blockIdx.x * SCAN_ELEMS + threadIdx.x + j * SCAN_T;
        if (i < NBINS) rp[i] += off;
    }
}

// -------- dinv = rsqrt(1+deg), dsq = sqrt(1+deg); deg = rp[(i+1)*8]-rp[i*8] -----
__global__ void k_dinv(const int* __restrict__ rp, float* __restrict__ dinv,
                       float* __restrict__ dsq) {
    int i = blockIdx.x * blockDim.x + threadIdx.x;
    if (i < N_NODES) {
        int deg = rp[(i + 1) * NZS] - rp[i * NZS];
        float d = 1.0f + (float)deg;
        dinv[i] = rsqrtf(d);
        dsq[i]  = sqrtf(d);
    }
}

// ------- XCD-local CSR fill: same zone partitioning, own atomic counters -------
__global__ __launch_bounds__(256)
void k_fill(const int* __restrict__ eidx, const int* __restrict__ rp,
            int* __restrict__ cntf, int* __restrict__ col) {
    uint zone = blockIdx.x;
    int  base = blockIdx.y * FCHUNK;
#pragma unroll
    for (int i = 0; i < FCHUNK / 1024; ++i) {
        int e0 = base + (i * 256 + (int)threadIdx.x) * 4;
        if (e0 < N_EDGES) {
            int4 d4 = *(const int4*)&eidx[N_EDGES + e0];
            int4 s4 = *(const int4*)&eidx[e0];
            if ((uint)d4.x / ZDIV == zone) {
                int b = d4.x * NZS + (int)((uint)s4.x / SZDIV);
                int p = atomicAdd(&cntf[b], 1);
                col[rp[b] + p] = s4.x;
            }
            if ((uint)d4.y / ZDIV == zone) {
                int b = d4.y * NZS + (int)((uint)s4.y / SZDIV);
                int p = atomicAdd(&cntf[b], 1);
                col[rp[b] + p] = s4.y;
            }
            if ((uint)d4.z / ZDIV == zone) {
                int b = d4.z * NZS + (int)((uint)s4.z / SZDIV);
                int p = atomicAdd(&cntf[b], 1);
                col[rp[b] + p] = s4.z;
            }
            if ((uint)d4.w / ZDIV == zone) {
                int b = d4.w * NZS + (int)((uint)s4.w / SZDIV);
                int p = atomicAdd(&cntf[b], 1);
                col[rp[b] + p] = s4.w;
            }
        }
    }
}

// ---------------- GEMM1: u0 = bf16( dinv * relu(x @ W1 + b1) ) ----------------
#define KCH 64
__global__ __launch_bounds__(256)
void k_gemm1(const float* __restrict__ x, const float* __restrict__ W,
             const float* __restrict__ bias, const float* __restrict__ dinv,
             uint* __restrict__ out) {
    __shared__ __align__(16) float wlds[KCH][HDIM];     // 32 KB
    __shared__ __align__(16) float xs[32][KCH + 1];     // ~8.3 KB
    int tid  = threadIdx.x;
    int tx   = tid & 31, ty = tid >> 5;
    int row0 = blockIdx.x * 32;

    float4 bc = *(const float4*)&bias[tx * 4];

    float acc[4][4] = {};
    for (int kc = 0; kc < HDIM; kc += KCH) {
#pragma unroll
        for (int i = 0; i < 8; ++i) {
            int id = tid + i * 256;
            int kk = id >> 5, n4 = id & 31;
            *(float4*)&wlds[kk][n4 * 4] =
                *(const float4*)&W[(size_t)(kc + kk) * HDIM + n4 * 4];
        }
#pragma unroll
        for (int i = 0; i < 2; ++i) {
            int id = tid + i * 256;
            int r = id >> 4, c4 = id & 15;
            float4 v = *(const float4*)&x[(size_t)(row0 + r) * HDIM + kc + c4 * 4];
            xs[r][c4 * 4 + 0] = v.x;
            xs[r][c4 * 4 + 1] = v.y;
            xs[r][c4 * 4 + 2] = v.z;
            xs[r][c4 * 4 + 3] = v.w;
        }
        __syncthreads();
#pragma unroll 8
        for (int kk = 0; kk < KCH; ++kk) {
            float4 b4 = *(const float4*)&wlds[kk][tx * 4];
            float a0 = xs[ty * 4 + 0][kk];
            float a1 = xs[ty * 4 + 1][kk];
            float a2 = xs[ty * 4 + 2][kk];
            float a3 = xs[ty * 4 + 3][kk];
            acc[0][0] += a0 * b4.x; acc[0][1] += a0 * b4.y; acc[0][2] += a0 * b4.z; acc[0][3] += a0 * b4.w;
            acc[1][0] += a1 * b4.x; acc[1][1] += a1 * b4.y; acc[1][2] += a1 * b4.z; acc[1][3] += a1 * b4.w;
            acc[2][0] += a2 * b4.x; acc[2][1] += a2 * b4.y; acc[2][2] += a2 * b4.z; acc[2][3] += a2 * b4.w;
            acc[3][0] += a3 * b4.x; acc[3][1] += a3 * b4.y; acc[3][2] += a3 * b4.z; acc[3][3] += a3 * b4.w;
        }
        __syncthreads();
    }
#pragma unroll
    for (int r = 0; r < 4; ++r) {
        int row = row0 + ty * 4 + r;
        float di = dinv[row];
        float v0 = fmaxf(acc[r][0] + bc.x, 0.0f) * di;
        float v1 = fmaxf(acc[r][1] + bc.y, 0.0f) * di;
        float v2 = fmaxf(acc[r][2] + bc.z, 0.0f) * di;
        float v3 = fmaxf(acc[r][3] + bc.w, 0.0f) * di;
        uint2 p;
        p.x = f2_to_bf2(v0, v1);
        p.y = f2_to_bf2(v2, v3);
        *(uint2*)&out[(size_t)row * 64 + tx * 2] = p;   // row = 64 uints (128 bf16)
    }
}

// ---------------- GEMM2: out = (dsq * bf16 u) @ W2 + b2, fp32 out ----------------
__global__ __launch_bounds__(256)
void k_gemm2(const uint* __restrict__ u, const float* __restrict__ W,
             const float* __restrict__ bias, const float* __restrict__ dsq,
             float* __restrict__ out) {
    __shared__ __align__(16) float wlds[KCH][HDIM];
    __shared__ __align__(16) float xs[32][KCH + 1];
    int tid  = threadIdx.x;
    int tx   = tid & 31, ty = tid >> 5;
    int row0 = blockIdx.x * 32;

    float4 bc = *(const float4*)&bias[tx * 4];

    float acc[4][4] = {};
    for (int kc = 0; kc < HDIM; kc += KCH) {
#pragma unroll
        for (int i = 0; i < 8; ++i) {
            int id = tid + i * 256;
            int kk = id >> 5, n4 = id & 31;
            *(float4*)&wlds[kk][n4 * 4] =
                *(const float4*)&W[(size_t)(kc + kk) * HDIM + n4 * 4];
        }
#pragma unroll
        for (int i = 0; i < 2; ++i) {
            int id = tid + i * 256;
            int r = id >> 4, c4 = id & 15;
            float ds = dsq[row0 + r];
            uint2 v = *(const uint2*)&u[(size_t)(row0 + r) * 64 + (kc >> 1) + c4 * 2];
            float2 f0 = bf2_to_f2(v.x);
            float2 f1 = bf2_to_f2(v.y);
            xs[r][c4 * 4 + 0] = f0.x * ds;
            xs[r][c4 * 4 + 1] = f0.y * ds;
            xs[r][c4 * 4 + 2] = f1.x * ds;
            xs[r][c4 * 4 + 3] = f1.y * ds;
        }
        __syncthreads();
#pragma unroll 8
        for (int kk = 0; kk < KCH; ++kk) {
            float4 b4 = *(const float4*)&wlds[kk][tx * 4];
            float a0 = xs[ty * 4 + 0][kk];
            float a1 = xs[ty * 4 + 1][kk];
            float a2 = xs[ty * 4 + 2][kk];
            float a3 = xs[ty * 4 + 3][kk];
            acc[0][0] += a0 * b4.x; acc[0][1] += a0 * b4.y; acc[0][2] += a0 * b4.z; acc[0][3] += a0 * b4.w;
            acc[1][0] += a1 * b4.x; acc[1][1] += a1 * b4.y; acc[1][2] += a1 * b4.z; acc[1][3] += a1 * b4.w;
            acc[2][0] += a2 * b4.x; acc[2][1] += a2 * b4.y; acc[2][2] += a2 * b4.z; acc[2][3] += a2 * b4.w;
            acc[3][0] += a3 * b4.x; acc[3][1] += a3 * b4.y; acc[3][2] += a3 * b4.z; acc[3][3] += a3 * b4.w;
        }
        __syncthreads();
    }
#pragma unroll
    for (int r = 0; r < 4; ++r) {
        int row = row0 + ty * 4 + r;
        float4 v;
        v.x = acc[r][0] + bc.x;
        v.y = acc[r][1] + bc.y;
        v.z = acc[r][2] + bc.z;
        v.w = acc[r][3] + bc.w;
        *(float4*)&out[(size_t)row * HDIM + tx * 4] = v;
    }
}

// ---- APPNP step, u stored bf16x2: u' = 0.9*dinv^2*(sum u[s] + u[i]) + 0.1*u0 ----
// One wave per node; edges contiguous [rp[n*8], rp[(n+1)*8]) and zone-sorted
// (ascending src) so resident waves sweep uin front-to-back in loose sync.
__global__ __launch_bounds__(256)
void k_step(const uint* __restrict__ uin, const uint* __restrict__ u0,
            uint* __restrict__ uout, const int* __restrict__ col,
            const int* __restrict__ rp, const float* __restrict__ dinv) {
    int wid  = (blockIdx.x * blockDim.x + threadIdx.x) >> 6;
    int node = __builtin_amdgcn_readfirstlane(wid);
    int lane = threadIdx.x & 63;
    if (node >= N_NODES) return;

    size_t self = (size_t)node * 64 + lane;
    uint usv = uin[self];                              // self row (gather-hot region)
    uint uzv = __builtin_nontemporal_load(&u0[self]);  // one-touch stream
    float di = dinv[node];
    float w  = 0.9f * di * di;

    int beg = rp[node * NZS], end = rp[node * NZS + NZS];
    float2 us = bf2_to_f2(usv);
    float accx = us.x, accy = us.y;                    // self-loop term

    int e = beg;
    for (; e + 8 <= end; e += 8) {
        int s0 = col[e + 0], s1 = col[e + 1], s2 = col[e + 2], s3 = col[e + 3];
        int s4 = col[e + 4], s5 = col[e + 5], s6 = col[e + 6], s7 = col[e + 7];
        uint b0 = uin[(size_t)s0 * 64 + lane];
        uint b1 = uin[(size_t)s1 * 64 + lane];
        uint b2 = uin[(size_t)s2 * 64 + lane];
        uint b3 = uin[(size_t)s3 * 64 + lane];
        uint b4 = uin[(size_t)s4 * 64 + lane];
        uint b5 = uin[(size_t)s5 * 64 + lane];
        uint b6 = uin[(size_t)s6 * 64 + lane];
        uint b7 = uin[(size_t)s7 * 64 + lane];
        float2 a0 = bf2_to_f2(b0), a1 = bf2_to_f2(b1);
        float2 a2 = bf2_to_f2(b2), a3 = bf2_to_f2(b3);
        float2 a4 = bf2_to_f2(b4), a5 = bf2_to_f2(b5);
        float2 a6 = bf2_to_f2(b6), a7 = bf2_to_f2(b7);
        accx += ((a0.x + a1.x) + (a2.x + a3.x)) + ((a4.x + a5.x) + (a6.x + a7.x));
        accy += ((a0.y + a1.y) + (a2.y + a3.y)) + ((a4.y + a5.y) + (a6.y + a7.y));
    }
    if (e + 4 <= end) {
        int s0 = col[e], s1 = col[e + 1], s2 = col[e + 2], s3 = col[e + 3];
        uint b0 = uin[(size_t)s0 * 64 + lane];
        uint b1 = uin[(size_t)s1 * 64 + lane];
        uint b2 = uin[(size_t)s2 * 64 + lane];
        uint b3 = uin[(size_t)s3 * 64 + lane];
        float2 a0 = bf2_to_f2(b0), a1 = bf2_to_f2(b1);
        float2 a2 = bf2_to_f2(b2), a3 = bf2_to_f2(b3);
        accx += (a0.x + a1.x) + (a2.x + a3.x);
        accy += (a0.y + a1.y) + (a2.y + a3.y);
        e += 4;
    }
    if (e + 2 <= end) {
        int s0 = col[e], s1 = col[e + 1];
        uint b0 = uin[(size_t)s0 * 64 + lane];
        uint b1 = uin[(size_t)s1 * 64 + lane];
        float2 a0 = bf2_to_f2(b0), a1 = bf2_to_f2(b1);
        accx += a0.x + a1.x;
        accy += a0.y + a1.y;
        e += 2;
    }
    if (e < end) {
        uint b0 = uin[(size_t)col[e] * 64 + lane];
        float2 a0 = bf2_to_f2(b0);
        accx += a0.x;
        accy += a0.y;
    }
    float2 uz = bf2_to_f2(uzv);
    float ox = w * accx + 0.1f * uz.x;
    float oy = w * accy + 0.1f * uz.y;
    __builtin_nontemporal_store(f2_to_bf2(ox, oy), &uout[self]);
}

extern "C" void kernel_launch(void* const* d_in, const int* in_sizes, int n_in,
                              void* d_out, int out_size, void* d_ws, size_t ws_size,
                              hipStream_t stream) {
    (void)in_sizes; (void)n_in; (void)out_size; (void)ws_size;
    const float* x  = (const float*)d_in[0];
    const int*   ei = (const int*)d_in[1];
    const float* W1 = (const float*)d_in[2];
    const float* b1 = (const float*)d_in[3];
    const float* W2 = (const float*)d_in[4];
    const float* b2 = (const float*)d_in[5];
    float* out = (float*)d_out;

    char* ws = (char*)d_ws;
    size_t off = 0;
    auto alloc = [&](size_t bytes) -> void* {
        void* p = ws + off;
        off += (bytes + 255) & ~(size_t)255;
        return p;
    };
    uint*  u0   = (uint*)alloc(sizeof(uint) * (size_t)N_NODES * 64);   // bf16x2 rows
    uint*  uA   = (uint*)alloc(sizeof(uint) * (size_t)N_NODES * 64);
    uint*  uB   = (uint*)alloc(sizeof(uint) * (size_t)N_NODES * 64);
    int*   col  = (int*)alloc(sizeof(int) * N_EDGES);
    int*   rp   = (int*)alloc(sizeof(int) * (NBINS + 1));
    float* dinv = (float*)alloc(sizeof(float) * N_NODES);
    float* dsq  = (float*)alloc(sizeof(float) * N_NODES);
    int*   bsum = (int*)alloc(sizeof(int) * SCAN_NB);
    int*   boff = (int*)alloc(sizeof(int) * SCAN_NB);
    // cnt dead after k_scan1 (uA first written by k_step k=0, after fill);
    // cntf dead after k_fill (uB first written by k_step k=1).
    int*   cnt  = (int*)uA;
    int*   cntf = (int*)uB;

    hipMemsetAsync(cnt,  0, sizeof(int) * NBINS, stream);
    hipMemsetAsync(cntf, 0, sizeof(int) * NBINS, stream);

    {
        dim3 g(NZONE, FECH);
        k_count<<<g, 256, 0, stream>>>(ei, cnt);
    }
    k_scan1<<<SCAN_NB, SCAN_T, 0, stream>>>(cnt, rp, bsum);
    k_scan2<<<1, SCAN_T, 0, stream>>>(bsum, boff, rp);
    k_scan3<<<SCAN_NB, SCAN_T, 0, stream>>>(rp, boff);
    k_dinv<<<(N_NODES + 255) / 256, 256, 0, stream>>>(rp, dinv, dsq);
    {
        dim3 g(NZONE, FECH);
        k_fill<<<g, 256, 0, stream>>>(ei, rp, cntf, col);
    }

    k_gemm1<<<N_NODES / 32, 256, 0, stream>>>(x, W1, b1, dinv, u0);

    const uint* uin = u0;
    uint* uout = uA;
    for (int k = 0; k < KSTEPS; ++k) {
        k_step<<<N_NODES / 4, 256, 0, stream>>>(uin, u0, uout, col, rp, dinv);
        uin = uout;
        uout = (uout == uA) ? uB : uA;
    }
    k_gemm2<<<N_NODES / 32, 256, 0, stream>>>(uin, W2, b2, dsq, out);
}